// Round 1
// baseline (220.286 us; speedup 1.0000x reference)
//
#include <hip/hip_runtime.h>
#include <hip/hip_bf16.h>
#include <stdint.h>

// Flip to 0 if absmax lands at ~1e-3..1e-2 (wrong JAX PRNG variant:
// pre-0.4.36 non-partitionable threefry split/random_bits scheme).
#define JAX_PARTITIONABLE 1

#define BB 2
#define SS 192
#define DD 256
#define NROW (BB * SS)   // 384
#define NE (NROW * DD)   // 98304

// ---------------- threefry2x32-20 (Random123 / JAX) ----------------
__device__ __forceinline__ uint32_t rotl32(uint32_t v, int d) {
  return (v << d) | (v >> (32 - d));
}

__device__ inline void threefry2x32(uint32_t k0, uint32_t k1, uint32_t x0, uint32_t x1,
                                    uint32_t* o0, uint32_t* o1) {
  uint32_t ks2 = k0 ^ k1 ^ 0x1BD11BDAu;
  x0 += k0; x1 += k1;
  const int ra[4] = {13, 15, 26, 6};
  const int rb[4] = {17, 29, 16, 24};
#pragma unroll
  for (int i = 0; i < 4; i++) { x0 += x1; x1 = rotl32(x1, ra[i]); x1 ^= x0; }
  x0 += k1; x1 += ks2 + 1u;
#pragma unroll
  for (int i = 0; i < 4; i++) { x0 += x1; x1 = rotl32(x1, rb[i]); x1 ^= x0; }
  x0 += ks2; x1 += k0 + 2u;
#pragma unroll
  for (int i = 0; i < 4; i++) { x0 += x1; x1 = rotl32(x1, ra[i]); x1 ^= x0; }
  x0 += k0; x1 += k1 + 3u;
#pragma unroll
  for (int i = 0; i < 4; i++) { x0 += x1; x1 = rotl32(x1, rb[i]); x1 ^= x0; }
  x0 += k1; x1 += ks2 + 4u;
#pragma unroll
  for (int i = 0; i < 4; i++) { x0 += x1; x1 = rotl32(x1, ra[i]); x1 ^= x0; }
  x0 += ks2; x1 += k0 + 5u;
  *o0 = x0; *o1 = x1;
}

// XLA ErfInv (f32), same polynomial all backends use.
__device__ inline float erfinv_xla_f32(float x) {
  float w = -log1pf(-x * x);
  float p;
  if (w < 5.0f) {
    w = w - 2.5f;
    p = 2.81022636e-08f;
    p = 3.43273939e-07f + p * w;
    p = -3.5233877e-06f + p * w;
    p = -4.39150654e-06f + p * w;
    p = 0.00021858087f + p * w;
    p = -0.00125372503f + p * w;
    p = -0.00417768164f + p * w;
    p = 0.246640727f + p * w;
    p = 1.50140941f + p * w;
  } else {
    w = sqrtf(w) - 3.0f;
    p = -0.000200214257f;
    p = 0.000100950558f + p * w;
    p = 0.00134934322f + p * w;
    p = -0.00367342844f + p * w;
    p = 0.00573950773f + p * w;
    p = -0.0076224613f + p * w;
    p = 0.00943887047f + p * w;
    p = 1.00167406f + p * w;
    p = 2.83297682f + p * w;
  }
  return p * x;
}

// JAX normal: uniform in [nextafter(-1,0), 1) then sqrt(2)*erfinv, all f32.
__device__ inline float jax_normal_from_bits(uint32_t bits) {
  float f = __uint_as_float((bits >> 9) | 0x3f800000u) - 1.0f;
  const float lo = -0.99999994f;  // nextafter(-1, 0) in f32
  float u = f * (1.0f - lo) + lo;
  u = fmaxf(lo, u);
  return 1.4142135623730951f * erfinv_xla_f32(u);
}

// Generates: noise = 1e-5*normal(nk0,[B,S,D]); vrand = normal(nk1,[B,S,D,1]);
// ode = 1e-4*normal(nk2,[B,S,1]); nk = split(key(42), 3).
__global__ void rng_kernel(float* __restrict__ noise, float* __restrict__ vrnd,
                           float* __restrict__ ode) {
  int idx = blockIdx.x * blockDim.x + threadIdx.x;
  const int total = 2 * NE + NROW;
  if (idx >= total) return;
  uint32_t nk0a, nk0b, nk1a, nk1b, nk2a, nk2b;
#if JAX_PARTITIONABLE
  threefry2x32(0u, 42u, 0u, 0u, &nk0a, &nk0b);
  threefry2x32(0u, 42u, 0u, 1u, &nk1a, &nk1b);
  threefry2x32(0u, 42u, 0u, 2u, &nk2a, &nk2b);
#else
  uint32_t a0, a1, b0, b1, c0, c1;
  threefry2x32(0u, 42u, 0u, 3u, &a0, &a1);
  threefry2x32(0u, 42u, 1u, 4u, &b0, &b1);
  threefry2x32(0u, 42u, 2u, 5u, &c0, &c1);
  // out = [a0,b0,c0,a1,b1,c1] reshaped (3,2)
  nk0a = a0; nk0b = b0; nk1a = c0; nk1b = a1; nk2a = b1; nk2b = c1;
#endif
  uint32_t o0, o1, bits;
  if (idx < NE) {
    uint32_t i = (uint32_t)idx;
#if JAX_PARTITIONABLE
    threefry2x32(nk0a, nk0b, 0u, i, &o0, &o1); bits = o0 ^ o1;
#else
    const uint32_t H = NE / 2;
    if (i < H) { threefry2x32(nk0a, nk0b, i, i + H, &o0, &o1); bits = o0; }
    else       { threefry2x32(nk0a, nk0b, i - H, i, &o0, &o1); bits = o1; }
#endif
    noise[i] = 1e-5f * jax_normal_from_bits(bits);
  } else if (idx < 2 * NE) {
    uint32_t i = (uint32_t)(idx - NE);
#if JAX_PARTITIONABLE
    threefry2x32(nk1a, nk1b, 0u, i, &o0, &o1); bits = o0 ^ o1;
#else
    const uint32_t H = NE / 2;
    if (i < H) { threefry2x32(nk1a, nk1b, i, i + H, &o0, &o1); bits = o0; }
    else       { threefry2x32(nk1a, nk1b, i - H, i, &o0, &o1); bits = o1; }
#endif
    vrnd[i] = jax_normal_from_bits(bits);
  } else {
    uint32_t i = (uint32_t)(idx - 2 * NE);
#if JAX_PARTITIONABLE
    threefry2x32(nk2a, nk2b, 0u, i, &o0, &o1); bits = o0 ^ o1;
#else
    const uint32_t H = NROW / 2;
    if (i < H) { threefry2x32(nk2a, nk2b, i, i + H, &o0, &o1); bits = o0; }
    else       { threefry2x32(nk2a, nk2b, i - H, i, &o0, &o1); bits = o1; }
#endif
    ode[i] = 1e-4f * jax_normal_from_bits(bits);
  }
}

// ---------------- reductions (256 threads = 4 waves of 64) ----------------
__device__ inline double blockReduceSum256(double v, double* red, int tid) {
#pragma unroll
  for (int off = 32; off > 0; off >>= 1) v += __shfl_down(v, off, 64);
  __syncthreads();
  if ((tid & 63) == 0) red[tid >> 6] = v;
  __syncthreads();
  if (tid == 0) red[5] = (red[0] + red[1]) + (red[2] + red[3]);
  __syncthreads();
  return red[5];
}

__device__ inline double reduceS_sum(const double* arr, double* red, int tid) {
  __syncthreads();
  if (tid < 64) {
    double v = arr[tid] + arr[tid + 64] + arr[tid + 128];
#pragma unroll
    for (int off = 32; off > 0; off >>= 1) v += __shfl_down(v, off, 64);
    if (tid == 0) red[6] = v;
  }
  __syncthreads();
  return red[6];
}

__device__ inline double reduceS_min(const double* arr, double* red, int tid) {
  __syncthreads();
  if (tid < 64) {
    double v = fmin(arr[tid], fmin(arr[tid + 64], arr[tid + 128]));
#pragma unroll
    for (int off = 32; off > 0; off >>= 1) v = fmin(v, __shfl_down(v, off, 64));
    if (tid == 0) red[6] = v;
  }
  __syncthreads();
  return red[6];
}

// ---------------- small GEMMs ----------------
__global__ void transpose4(const float* __restrict__ Wq, const float* __restrict__ Wk,
                           const float* __restrict__ Wv, const float* __restrict__ Wo,
                           float* __restrict__ WqT, float* __restrict__ WkT,
                           float* __restrict__ WvT, float* __restrict__ WoT) {
  int m = blockIdx.x >> 8;
  int i = blockIdx.x & 255;
  int j = threadIdx.x;
  const float* S_; float* D_;
  if (m == 0) { S_ = Wq; D_ = WqT; }
  else if (m == 1) { S_ = Wk; D_ = WkT; }
  else if (m == 2) { S_ = Wv; D_ = WvT; }
  else { S_ = Wo; D_ = WoT; }
  D_[i * DD + j] = S_[j * DD + i];
}

__global__ __launch_bounds__(256) void gemm_qkv(
    const float* __restrict__ q_in, const float* __restrict__ k_in, const float* __restrict__ v_in,
    const float* __restrict__ WqT, const float* __restrict__ WkT, const float* __restrict__ WvT,
    const float* __restrict__ bq, const float* __restrict__ bk, const float* __restrict__ bv,
    float* __restrict__ qb, float* __restrict__ kb, float* __restrict__ vb) {
  int row = blockIdx.x;
  int m = blockIdx.y;
  int j = threadIdx.x;
  const float* x; const float* WT; const float* bias; float* out;
  if (m == 0) { x = q_in; WT = WqT; bias = bq; out = qb; }
  else if (m == 1) { x = k_in; WT = WkT; bias = bk; out = kb; }
  else { x = v_in; WT = WvT; bias = bv; out = vb; }
  __shared__ float xs[DD];
  xs[j] = x[(size_t)row * DD + j];
  __syncthreads();
  double acc = 0.0;
#pragma unroll 4
  for (int i = 0; i < DD; ++i) acc += (double)xs[i] * (double)WT[i * DD + j];
  out[(size_t)row * DD + j] = (float)(acc + (double)bias[j]);
}

__global__ __launch_bounds__(256) void gemm_out(
    const float* __restrict__ hf, const float* __restrict__ WoT,
    const float* __restrict__ bo, float* __restrict__ out) {
  int row = blockIdx.x;
  int j = threadIdx.x;
  __shared__ float xs[DD];
  xs[j] = hf[(size_t)row * DD + j];
  __syncthreads();
  double acc = 0.0;
#pragma unroll 4
  for (int i = 0; i < DD; ++i) acc += (double)xs[i] * (double)WoT[i * DD + j];
  out[(size_t)row * DD + j] = (float)(acc + (double)bo[j]);
}

// q_hyp/k_hyp = expmap0(clip_tangent(row)); also k_hypT and y2 = ||k_hyp||^2.
__global__ __launch_bounds__(256) void rows_kernel(
    const float* __restrict__ qb, const float* __restrict__ kb,
    float* __restrict__ q_hyp, float* __restrict__ k_hyp,
    float* __restrict__ k_hypT, double* __restrict__ y2g) {
  __shared__ double red[8];
  int row = blockIdx.x;
  int b = row / SS;
  int s = row % SS;
  int tid = threadIdx.x;
  // q row
  double qv = (double)qb[(size_t)row * DD + tid];
  double n2 = blockReduceSum256(qv * qv, red, tid);
  double n = sqrt(n2);
  double cf = fmin(4.0 / (n + 1e-8), 1.0);
  double ncl = fmax(n * cf, 1e-15);
  double sc = tanh(ncl) * cf / ncl;
  q_hyp[(size_t)row * DD + tid] = (float)(qv * sc);
  // k row
  double kv = (double)kb[(size_t)row * DD + tid];
  n2 = blockReduceSum256(kv * kv, red, tid);
  n = sqrt(n2);
  cf = fmin(4.0 / (n + 1e-8), 1.0);
  ncl = fmax(n * cf, 1e-15);
  sc = tanh(ncl) * cf / ncl;
  float khf = (float)(kv * sc);
  k_hyp[(size_t)row * DD + tid] = khf;
  k_hypT[((size_t)b * DD + tid) * SS + s] = khf;
  double y2 = blockReduceSum256((double)khf * (double)khf, red, tid);
  if (tid == 0) y2g[row] = y2;
}

// ---------------- main fused per-(b,q) kernel ----------------
__global__ __launch_bounds__(256) void resonance_main(
    const float* __restrict__ q_hyp, const float* __restrict__ k_hyp,
    const float* __restrict__ k_hypT, const float* __restrict__ kmat,
    const float* __restrict__ vmat, const double* __restrict__ y2g,
    const float* __restrict__ noise, const float* __restrict__ vrnd,
    const float* __restrict__ ode, const float* __restrict__ tau_p,
    const float* __restrict__ ts_p, float* __restrict__ hfused) {
  __shared__ double xq[DD], xc[DD], vr[DD];
  __shared__ double y2s[SS], wun[SS], wns[SS], alf[SS], bet[SS], sA[SS], sB[SS];
  __shared__ double red[8];
  const int tid = threadIdx.x;
  const int blk = blockIdx.x;
  const int b = blk / SS;
  const int qi = blk % SS;
  const size_t rowOff = (size_t)blk * DD;
  const float* khB = k_hyp + (size_t)b * SS * DD;
  const float* khT = k_hypT + (size_t)b * DD * SS;
  const float* kB = kmat + (size_t)b * SS * DD;
  const float* vB = vmat + (size_t)b * SS * DD;

  double xqv = (double)q_hyp[rowOff + tid];
  xq[tid] = xqv;
  if (tid < SS) y2s[tid] = y2g[b * SS + tid];
  double x2q = blockReduceSum256(xqv * xqv, red, tid);  // syncs cover xq/y2s writes

  // ---- pairwise hyperbolic distance row, stabilized exp weights ----
  if (tid < SS) {
    double dot = 0.0;
#pragma unroll 4
    for (int d = 0; d < DD; ++d) dot += xq[d] * (double)khT[d * SS + tid];
    double y2 = y2s[tid];
    double A = 1.0 - 2.0 * dot + y2;
    double Dn = fmax(1.0 - 2.0 * dot + x2q * y2, 1e-15);
    double Bc = 1.0 - x2q;
    double u2 = (A * A * x2q - 2.0 * A * Bc * dot + Bc * Bc * y2) / (Dn * Dn);
    double unr = sqrt(fmax(u2, 0.0));
    sA[tid] = 2.0 * atanh(fmin(unr, 1.0 - 1e-7));
  }
  double mind = reduceS_min(sA, red, tid);
  if (tid < SS) wun[tid] = exp(-(sA[tid] - mind));
  double wsum = reduceS_sum(wun, red, tid);
  {
    double invw = 1.0 / (wsum + 1e-8);
    if (tid < SS) wns[tid] = wun[tid] * invw;
  }
  __syncthreads();

  // ---- h = wns . v  (register-resident; only used elementwise) ----
  double hreg = 0.0;
#pragma unroll 4
  for (int s = 0; s < SS; ++s) hreg += wns[s] * (double)vB[s * DD + tid];

  // ---- mu0 = expmap0(clip_tangent(wns . k)) ----
  double x2c;
  {
    double acc = 0.0;
#pragma unroll 4
    for (int s = 0; s < SS; ++s) acc += wns[s] * (double)kB[s * DD + tid];
    double n2 = blockReduceSum256(acc * acc, red, tid);
    double n = sqrt(n2);
    double cf = fmin(4.0 / (n + 1e-8), 1.0);
    double ncl = fmax(n * cf, 1e-15);
    double th = tanh(ncl);
    xc[tid] = acc * (th * cf / ncl);
    x2c = th * th;
  }
  __syncthreads();

  // ---- Karcher flow: 3 Riemannian SGD steps ----
  for (int it = 0; it < 3; ++it) {
    if (tid < SS) {
      double dot = 0.0;
#pragma unroll 4
      for (int d = 0; d < DD; ++d) dot += xc[d] * (double)khT[d * SS + tid];
      double y2 = y2s[tid];
      double A = 1.0 - 2.0 * dot + y2;
      double Dn = fmax(1.0 - 2.0 * dot + x2c * y2, 1e-15);
      double Bc = 1.0 - x2c;
      double u2 = (A * A * x2c - 2.0 * A * Bc * dot + Bc * Bc * y2) / (Dn * Dn);
      double unr = sqrt(fmax(u2, 0.0));
      double un = fmax(unr, 1e-15);
      double coef = fmax(Bc, 1e-15) * atanh(fmin(un, 1.0 - 1e-7)) / un;
      double cs = wns[tid] * coef / Dn;
      sA[tid] = cs;
      sB[tid] = cs * A;
    }
    double S1 = reduceS_sum(sB, red, tid);
    double g = 0.0;
#pragma unroll 4
    for (int s = 0; s < SS; ++s) g += sA[s] * (double)khB[s * DD + tid];
    double Bc = 1.0 - x2c;
    double vg = Bc * g - S1 * xc[tid];               // v_grad[d]
    double nv2 = blockReduceSum256(vg * vg, red, tid);
    double nv = 0.1 * sqrt(nv2);                      // ||0.1*v_grad||
    double cf = fmin(4.0 / (nv + 1e-8), 1.0);         // clip_tangent
    double nw = fmax(nv * cf, 1e-15);                 // _expmap's n
    double tsc = tanh(nw / fmax(Bc, 1e-15));          // tanh(lam*n/2)
    double zco = tsc * 0.1 * cf / nw;
    double z = zco * vg;
    double xz = blockReduceSum256(xc[tid] * z, red, tid);
    double z2 = tsc * tsc;
    double den = fmax(1.0 + 2.0 * xz + x2c * z2, 1e-15);
    double xnew = ((1.0 + 2.0 * xz + z2) * xc[tid] + (1.0 - x2c) * z) / den;
    x2c = blockReduceSum256(xnew * xnew, red, tid);
    xc[tid] = xnew;
    __syncthreads();
  }

  // ---- k_centroid = projx(mu + noise) ----
  {
    double cn = xc[tid] + (double)noise[rowOff + tid];
    double n2 = blockReduceSum256(cn * cn, red, tid);
    double nn = sqrt(n2);
    if (nn > 1.0 - 1e-5) cn *= (1.0 - 1e-5) / fmax(nn, 1e-15);
    xc[tid] = cn;
    x2c = blockReduceSum256(cn * cn, red, tid);
  }

  // ---- c2k distances, entropy, variance; alpha/beta for weighted_k ----
  if (tid < SS) {
    double dot = 0.0;
#pragma unroll 4
    for (int d = 0; d < DD; ++d) dot += xc[d] * (double)khT[d * SS + tid];
    double y2 = y2s[tid];
    double A = 1.0 - 2.0 * dot + y2;
    double Dn = fmax(1.0 - 2.0 * dot + x2c * y2, 1e-15);
    double Bc = 1.0 - x2c;
    double u2 = (A * A * x2c - 2.0 * A * Bc * dot + Bc * Bc * y2) / (Dn * Dn);
    double unr = sqrt(fmax(u2, 0.0));
    double c2k = 2.0 * atanh(fmin(unr, 1.0 - 1e-7));
    sA[tid] = wns[tid] * c2k * c2k;                      // variance terms
    sB[tid] = -wns[tid] * log(wns[tid] + 1e-8);          // entropy terms
    double un = fmax(unr, 1e-15);
    double gl = fmax(Bc, 1e-15) * atanh(fmin(un, 1.0 - 1e-7)) / (un * Dn);
    double sq = sqrt(wun[tid] + 1e-8);
    // weighted_k[s,d] = alf[s]*xc[d] + bet[s]*k_hyp[s,d]
    alf[tid] = -sq * gl * A;
    bet[tid] = sq * gl * Bc;
  }
  double variance = reduceS_sum(sA, red, tid);
  double entropy = reduceS_sum(sB, red, tid);
  double tau = (double)tau_p[0];
  double tension = variance - tau * exp(entropy);

  // ---- power iteration on weighted_k (rank-structured) ----
  {
    double v0 = (double)vrnd[rowOff + tid];
    double n2 = blockReduceSum256(v0 * v0, red, tid);
    vr[tid] = v0 / fmax(sqrt(n2), 1e-8);
  }
  __syncthreads();
  for (int it = 0; it < 3; ++it) {
    double dxv = blockReduceSum256(xc[tid] * vr[tid], red, tid);
    if (tid < SS) {
      double dot = 0.0;
#pragma unroll 4
      for (int d = 0; d < DD; ++d) dot += vr[d] * (double)khT[d * SS + tid];
      double pj = alf[tid] * dxv + bet[tid] * dot;       // proj_s
      sA[tid] = alf[tid] * pj;
      sB[tid] = bet[tid] * pj;
    }
    double T1 = reduceS_sum(sA, red, tid);
    double g = 0.0;
#pragma unroll 4
    for (int s = 0; s < SS; ++s) g += sB[s] * (double)khB[s * DD + tid];
    double vnew = T1 * xc[tid] + g;
    double n2 = blockReduceSum256(vnew * vnew, red, tid);
    vr[tid] = vnew / fmax(sqrt(n2), 1e-8);
    __syncthreads();
  }

  // ---- w_proj: transported principal dir or logmap0 fallback ----
  double wproj;
  {
    double wg = vr[tid] / fmax(1.0 - x2c, 1e-15);
    double nq = fmax(sqrt(x2q), 1e-15);
    double aq = atanh(fmin(nq, 1.0 - 1e-7)) / nq;
    double nc = fmax(sqrt(x2c), 1e-15);
    double ac = atanh(fmin(nc, 1.0 - 1e-7)) / nc;
    double f = aq * xq[tid] - ac * xc[tid];
    double n2 = blockReduceSum256(f * f, red, tid);
    double fb = f / fmax(sqrt(n2), 1e-8);
    wproj = (variance > 1e-5) ? wg : fb;
  }

  // ---- h_comp, x, pitchfork RK4 ----
  double hn2 = blockReduceSum256(hreg * hreg, red, tid);
  double hn = sqrt(hn2);
  double hsc = asinh(hn) / (hn + 1e-8);
  double hc = hsc * hreg;
  double x = blockReduceSum256(hc * wproj, red, tid);
  double xi = (x == 0.0) ? (double)ode[b * SS + qi] : x;
  const double dt = 0.5;
#pragma unroll
  for (int r = 0; r < 4; ++r) {
    double k1 = dt * (tension * xi - xi * xi * xi);
    double a2 = xi + 0.5 * k1;
    double k2 = dt * (tension * a2 - a2 * a2 * a2);
    double a3 = xi + 0.5 * k2;
    double k3 = dt * (tension * a3 - a3 * a3 * a3);
    double a4 = xi + k3;
    double k4 = dt * (tension * a4 - a4 * a4 * a4);
    xi += (k1 + 2.0 * k2 + 2.0 * k3 + k4) / 6.0;
  }
  double ts = (double)ts_p[0];
  double hp = (hc + (xi - x) * wproj) * ts;           // h_prime * tangent_scale
  double hp2 = blockReduceSum256(hp * hp, red, tid);
  double nhp = sqrt(hp2);
  double cf = fmin(4.0 / (nhp + 1e-8), 1.0);
  double ncl = fmax(nhp * cf, 1e-15);
  double th = tanh(ncl);
  double nb = fmax(th, 1e-15);
  double ab = atanh(fmin(nb, 1.0 - 1e-7)) / nb;
  double hob = ab * th * cf / ncl * hp;               // logmap0(expmap0(clip(.)))
  double gate = fmax(tanh(tension / fmax(tau, 1e-3)), 0.0);
  hfused[rowOff + tid] = (float)((1.0 - gate) * hreg + gate * hob);
}

// ---------------- launch ----------------
extern "C" void kernel_launch(void* const* d_in, const int* in_sizes, int n_in,
                              void* d_out, int out_size, void* d_ws, size_t ws_size,
                              hipStream_t stream) {
  const float* q_in = (const float*)d_in[0];
  const float* k_in = (const float*)d_in[1];
  const float* v_in = (const float*)d_in[2];
  const float* Wq = (const float*)d_in[3];
  const float* bq = (const float*)d_in[4];
  const float* Wk = (const float*)d_in[5];
  const float* bk = (const float*)d_in[6];
  const float* Wv = (const float*)d_in[7];
  const float* bv = (const float*)d_in[8];
  const float* Wo = (const float*)d_in[9];
  const float* bo = (const float*)d_in[10];
  const float* tau = (const float*)d_in[11];
  const float* ts = (const float*)d_in[12];
  float* out = (float*)d_out;
  (void)in_sizes; (void)n_in; (void)out_size; (void)ws_size;

  char* base = (char*)d_ws;
  size_t off = 0;
  auto alloc = [&](size_t bytes) -> void* {
    void* p = base + off;
    off += (bytes + 255) & ~(size_t)255;
    return p;
  };
  float* WqT = (float*)alloc((size_t)DD * DD * 4);
  float* WkT = (float*)alloc((size_t)DD * DD * 4);
  float* WvT = (float*)alloc((size_t)DD * DD * 4);
  float* WoT = (float*)alloc((size_t)DD * DD * 4);
  float* qb = (float*)alloc((size_t)NE * 4);
  float* kb = (float*)alloc((size_t)NE * 4);
  float* vb = (float*)alloc((size_t)NE * 4);
  float* qh = (float*)alloc((size_t)NE * 4);
  float* kh = (float*)alloc((size_t)NE * 4);
  float* khT = (float*)alloc((size_t)NE * 4);
  double* y2g = (double*)alloc((size_t)NROW * 8);
  float* noiseb = (float*)alloc((size_t)NE * 4);
  float* vrndb = (float*)alloc((size_t)NE * 4);
  float* odeb = (float*)alloc((size_t)NROW * 4);
  float* hf = (float*)alloc((size_t)NE * 4);

  hipLaunchKernelGGL(transpose4, dim3(4 * DD), dim3(DD), 0, stream,
                     Wq, Wk, Wv, Wo, WqT, WkT, WvT, WoT);
  hipLaunchKernelGGL(gemm_qkv, dim3(NROW, 3), dim3(DD), 0, stream,
                     q_in, k_in, v_in, WqT, WkT, WvT, bq, bk, bv, qb, kb, vb);
  hipLaunchKernelGGL(rows_kernel, dim3(NROW), dim3(DD), 0, stream,
                     qb, kb, qh, kh, khT, y2g);
  int total = 2 * NE + NROW;
  hipLaunchKernelGGL(rng_kernel, dim3((total + 255) / 256), dim3(256), 0, stream,
                     noiseb, vrndb, odeb);
  hipLaunchKernelGGL(resonance_main, dim3(NROW), dim3(DD), 0, stream,
                     qh, kh, khT, kb, vb, y2g, noiseb, vrndb, odeb, tau, ts, hf);
  hipLaunchKernelGGL(gemm_out, dim3(NROW), dim3(DD), 0, stream, hf, WoT, bo, out);
}